// Round 13
// baseline (277.968 us; speedup 1.0000x reference)
//
#include <hip/hip_runtime.h>
#include <hip/hip_fp16.h>
#include <type_traits>

#define NCH 64
#define MAXB 512   // max buckets (supports n <= 131072)
#define CHUNK 4096 // edges per block in hist/scatter
#define POOL_BLOCKS 2048

typedef _Float16 half8 __attribute__((ext_vector_type(8)));
typedef float floatx4 __attribute__((ext_vector_type(4)));

// ---------------- A: bucket histogram (bucket = dst >> 8) ----------------
__global__ __launch_bounds__(256) void bucket_hist(const int* __restrict__ dst, int E,
                                                   int NB, int* __restrict__ bhist) {
    __shared__ int lh[MAXB];
    int t = threadIdx.x;
    for (int i = t; i < NB; i += 256) lh[i] = 0;
    __syncthreads();
    int base = blockIdx.x * CHUNK;
    int end = min(base + CHUNK, E);
    for (int i = base + t; i < end; i += 256)
        atomicAdd(&lh[dst[i] >> 8], 1);
    __syncthreads();
    for (int i = t; i < NB; i += 256) {
        int v = lh[i];
        if (v) atomicAdd(&bhist[i], v);
    }
}

// ---------------- B: exclusive scan of bucket counts (1 block) ----------------
__global__ __launch_bounds__(MAXB) void bucket_scan(const int* __restrict__ bhist, int NB,
                                                    int* __restrict__ bbase,
                                                    int* __restrict__ bcursor) {
    __shared__ int s[MAXB];
    int t = threadIdx.x;
    int v = (t < NB) ? bhist[t] : 0;
    s[t] = v;
    __syncthreads();
    for (int o = 1; o < MAXB; o <<= 1) {
        int x = (t >= o) ? s[t - o] : 0;
        __syncthreads();
        s[t] += x;
        __syncthreads();
    }
    int excl = s[t] - v;
    if (t < NB) { bbase[t] = excl; bcursor[t] = excl; }
    if (t == NB - 1) bbase[NB] = s[t];  // = E
}

// ---------------- C: scatter packed (src<<8 | dst&255) into bucket-grouped tmp ----------
__global__ __launch_bounds__(256) void bucket_scatter(const int* __restrict__ src,
                                                      const int* __restrict__ dst, int E,
                                                      int NB, int* __restrict__ bcursor,
                                                      int* __restrict__ tmp) {
    __shared__ int lh[MAXB];
    __shared__ int lbase[MAXB];
    int t = threadIdx.x;
    for (int i = t; i < NB; i += 256) lh[i] = 0;
    __syncthreads();
    int base = blockIdx.x * CHUNK;
    int end = min(base + CHUNK, E);
    for (int i = base + t; i < end; i += 256)
        atomicAdd(&lh[dst[i] >> 8], 1);
    __syncthreads();
    for (int i = t; i < NB; i += 256) {
        int v = lh[i];
        lbase[i] = v ? atomicAdd(&bcursor[i], v) : 0;
        lh[i] = 0;  // reuse as local cursor
    }
    __syncthreads();
    for (int i = base + t; i < end; i += 256) {
        int s_ = src[i], d_ = dst[i];
        int b = d_ >> 8;
        int p = lbase[b] + atomicAdd(&lh[b], 1);
        tmp[p] = (s_ << 8) | (d_ & 255);
    }
}

// ---------------- D: per-bucket finalize: local CSR + dinv + srcs (byte offsets) -------
__global__ __launch_bounds__(256) void bucket_finalize(const int* __restrict__ tmp,
                                                       const int* __restrict__ bbase,
                                                       int n, int E, int NB,
                                                       int* __restrict__ offsets,
                                                       float* __restrict__ dinv,
                                                       int* __restrict__ srcs) {
    int b = blockIdx.x;
    int t = threadIdx.x;
    __shared__ int ldeg[256];
    __shared__ int lsc[256];
    __shared__ int lcur[256];
    ldeg[t] = 0;
    __syncthreads();
    int s0 = bbase[b], e0 = bbase[b + 1];
    for (int e = s0 + t; e < e0; e += 256)
        atomicAdd(&ldeg[tmp[e] & 255], 1);
    __syncthreads();
    int v = ldeg[t];
    lsc[t] = v;
    __syncthreads();
    for (int o = 1; o < 256; o <<= 1) {
        int x = (t >= o) ? lsc[t - o] : 0;
        __syncthreads();
        lsc[t] += x;
        __syncthreads();
    }
    int excl = lsc[t] - v;
    lcur[t] = excl;
    int node = (b << 8) + t;
    if (node < n) {
        offsets[node] = s0 + excl;
        dinv[node] = rsqrtf((float)v + 1.0f);  // +1 self-loop
    }
    if (b == NB - 1 && t == 0) offsets[n] = E;
    __syncthreads();
    for (int e = s0 + t; e < e0; e += 256) {
        int r = tmp[e];
        int p = s0 + atomicAdd(&lcur[r & 255], 1);
        srcs[p] = (int)(((unsigned)r) >> 8) << 7;  // byte offset of fp16 row (src*128)
    }
}

// ---------------- W transpose + fp16 convert (both layers, one launch) ----------------
__global__ __launch_bounds__(256) void convert_wt(const float* __restrict__ W1,
                                                  const float* __restrict__ W2,
                                                  _Float16* __restrict__ wt1,
                                                  _Float16* __restrict__ wt2) {
    int idx = blockIdx.x * 256 + threadIdx.x;  // 0..8191
    int j = idx & 4095;                        // j = k*64 + c
    int k = j >> 6, c = j & 63;
    if (idx < 4096) wt1[c * NCH + k] = (_Float16)W1[j];
    else            wt2[c * NCH + k] = (_Float16)W2[j];
}

// ---------------- MFMA GEMM: Yh[row,:] = half((X[row,:] @ W) * dscale[row]) ----------------
// One wave per 16-row tile; 4 waves/block => 64 rows/block.
// A-frag (16x16x32 f16): lane l holds X[row0+(l&15)][k0+(l>>4)*8 + j], j=0..7
// B-frag: lane l holds W[k0+(l>>4)*8+j][c0+(l&15)] = wt[(c0+(l&15))*64 + k0+(l>>4)*8 + j]
// D: lane l reg i -> Y[row0+(l>>4)*4+i][c0+(l&15)]
template <typename T>
__global__ __launch_bounds__(256) void gemm64_mfma(const T* __restrict__ X,
                                                   const _Float16* __restrict__ wt,
                                                   const float* __restrict__ dscale,
                                                   __half* __restrict__ Y, int n) {
    int tid = threadIdx.x;
    int lane = tid & 63, wv = tid >> 6;
    int row0 = blockIdx.x * 64 + wv * 16;
    if (row0 >= n) return;

    int lrow = lane & 15;          // A row / B col / D col within tile
    int kgrp = (lane >> 4) * 8;    // k offset of this lane's 8 elements

    // B-frags: 4 col-tiles x 2 k-steps
    half8 bf[4][2];
#pragma unroll
    for (int ct = 0; ct < 4; ++ct) {
#pragma unroll
        for (int ks = 0; ks < 2; ++ks) {
            bf[ct][ks] = *(const half8*)(wt + (ct * 16 + lrow) * NCH + ks * 32 + kgrp);
        }
    }

    // A-frags: 2 k-steps
    int arow = row0 + lrow;
    half8 af[2];
    if constexpr (std::is_same_v<T, float>) {
        if (arow < n) {
#pragma unroll
            for (int ks = 0; ks < 2; ++ks) {
                const float4* xr = (const float4*)(X + (arow << 6) + ks * 32 + kgrp);
                float4 u0 = xr[0], u1 = xr[1];
                half8 a;
                a[0] = (_Float16)u0.x; a[1] = (_Float16)u0.y;
                a[2] = (_Float16)u0.z; a[3] = (_Float16)u0.w;
                a[4] = (_Float16)u1.x; a[5] = (_Float16)u1.y;
                a[6] = (_Float16)u1.z; a[7] = (_Float16)u1.w;
                af[ks] = a;
            }
        } else {
            af[0] = half8{}; af[1] = half8{};
        }
    } else {
        if (arow < n) {
#pragma unroll
            for (int ks = 0; ks < 2; ++ks)
                af[ks] = *(const half8*)((const _Float16*)X + (arow << 6) + ks * 32 + kgrp);
        } else {
            af[0] = half8{}; af[1] = half8{};
        }
    }

    floatx4 acc[4] = {floatx4{0,0,0,0}, floatx4{0,0,0,0}, floatx4{0,0,0,0}, floatx4{0,0,0,0}};
#pragma unroll
    for (int ks = 0; ks < 2; ++ks) {
#pragma unroll
        for (int ct = 0; ct < 4; ++ct) {
            acc[ct] = __builtin_amdgcn_mfma_f32_16x16x32_f16(af[ks], bf[ct][ks], acc[ct], 0, 0, 0);
        }
    }

    // scale rows + store fp16
    int rbase = row0 + (lane >> 4) * 4;
    float ds[4];
#pragma unroll
    for (int i = 0; i < 4; ++i) ds[i] = (rbase + i < n) ? dscale[rbase + i] : 0.f;
#pragma unroll
    for (int i = 0; i < 4; ++i) {
        int row = rbase + i;
        if (row < n) {
#pragma unroll
            for (int ct = 0; ct < 4; ++ct) {
                Y[(row << 6) + ct * 16 + lrow] = __float2half(acc[ct][i] * ds[i]);
            }
        }
    }
}

// ---------------- CSR gather (fp16 table, byte-offset edges) + self + bias + relu -------
__global__ __launch_bounds__(256) void gather_fused(const __half* __restrict__ XWs,
                                                    const int* __restrict__ srcs,
                                                    const int* __restrict__ offsets,
                                                    const float* __restrict__ dinv,
                                                    const float* __restrict__ b,
                                                    __half* __restrict__ H, int n) {
    int wid  = (blockIdx.x * 256 + threadIdx.x) >> 6;  // node
    int lane = threadIdx.x & 63;                       // channel
    if (wid >= n) return;
    const char* tab = (const char*)(XWs + lane);       // lane-offset base
    int start = offsets[wid], end = offsets[wid + 1];
    float acc0 = __half2float(*(const __half*)(tab + (wid << 7)));  // self-loop
    float acc1 = 0.f, acc2 = 0.f, acc3 = 0.f;
    int e = start;
    for (; e + 8 <= end; e += 8) {
        int o0 = srcs[e],     o1 = srcs[e + 1], o2 = srcs[e + 2], o3 = srcs[e + 3];
        int o4 = srcs[e + 4], o5 = srcs[e + 5], o6 = srcs[e + 6], o7 = srcs[e + 7];
        acc0 += __half2float(*(const __half*)(tab + o0));
        acc1 += __half2float(*(const __half*)(tab + o1));
        acc2 += __half2float(*(const __half*)(tab + o2));
        acc3 += __half2float(*(const __half*)(tab + o3));
        acc0 += __half2float(*(const __half*)(tab + o4));
        acc1 += __half2float(*(const __half*)(tab + o5));
        acc2 += __half2float(*(const __half*)(tab + o6));
        acc3 += __half2float(*(const __half*)(tab + o7));
    }
    for (; e + 2 <= end; e += 2) {
        int o0 = srcs[e], o1 = srcs[e + 1];
        acc0 += __half2float(*(const __half*)(tab + o0));
        acc1 += __half2float(*(const __half*)(tab + o1));
    }
    if (e < end) {
        int o0 = srcs[e];
        acc2 += __half2float(*(const __half*)(tab + o0));
    }
    float v = (acc0 + acc1) + (acc2 + acc3);
    v = v * dinv[wid] + b[lane];
    H[(wid << 6) + lane] = __float2half(v > 0.0f ? v : 0.0f);
}

// ---------------- pool stage 1: per-wave contiguous slice -> atomic flush per run -------
__global__ __launch_bounds__(256) void pool_partial(const __half* __restrict__ H,
                                                    const int* __restrict__ batch, int n,
                                                    float* __restrict__ pooled) {
    int gwave = blockIdx.x * 4 + (threadIdx.x >> 6);
    int lane  = threadIdx.x & 63;
    int nwaves = POOL_BLOCKS * 4;
    int per = (n + nwaves - 1) / nwaves;
    int start = gwave * per;
    int end = min(start + per, n);
    if (start >= end) return;
    int cur = batch[start];
    float acc = 0.f;
    for (int i = start; i < end; ++i) {
        int g = batch[i];
        if (g != cur) {
            atomicAdd(&pooled[(cur << 6) + lane], acc);
            acc = 0.f;
            cur = g;
        }
        acc += __half2float(H[(i << 6) + lane]);
    }
    atomicAdd(&pooled[(cur << 6) + lane], acc);
}

// ---------------- pool stage 2: mean + FC + relu (one wave per graph) ----------------
__global__ __launch_bounds__(64) void fc_out(const float* __restrict__ pooled,
                                             const int* __restrict__ batch, int n,
                                             const float* __restrict__ Wfc,
                                             const float* __restrict__ bfc,
                                             float* __restrict__ out) {
    int g = blockIdx.x;
    int c = threadIdx.x;
    int lo = 0, hi = n;
    while (lo < hi) { int m = (lo + hi) >> 1; if (batch[m] < g) lo = m + 1; else hi = m; }
    int start = lo;
    hi = n;
    while (lo < hi) { int m = (lo + hi) >> 1; if (batch[m] < g + 1) lo = m + 1; else hi = m; }
    int count = lo - start;

    __shared__ float ps[64];
    float inv = 1.0f / (float)(count > 1 ? count : 1);
    ps[c] = pooled[(g << 6) + c] * inv;
    __syncthreads();
    float acc = bfc[c];
#pragma unroll
    for (int k = 0; k < 64; ++k) acc += ps[k] * Wfc[k * NCH + c];
    out[(g << 6) + c] = acc > 0.0f ? acc : 0.0f;
}

static inline size_t align256(size_t x) { return (x + 255) & ~(size_t)255; }

extern "C" void kernel_launch(void* const* d_in, const int* in_sizes, int n_in,
                              void* d_out, int out_size, void* d_ws, size_t ws_size,
                              hipStream_t stream) {
    const float* x     = (const float*)d_in[0];
    const int*   ei    = (const int*)d_in[1];
    const int*   batch = (const int*)d_in[2];
    const float* W1    = (const float*)d_in[3];
    const float* b1    = (const float*)d_in[4];
    const float* W2    = (const float*)d_in[5];
    const float* b2    = (const float*)d_in[6];
    const float* Wfc   = (const float*)d_in[7];
    const float* bfc   = (const float*)d_in[8];
    float* out = (float*)d_out;

    int E = in_sizes[1] / 2;
    int n = in_sizes[0] / NCH;
    int ngraphs = out_size / NCH;
    const int* src = ei;
    const int* dst = ei + E;
    int NB = (n + 255) >> 8;

    char* p = (char*)d_ws;
    int*      bhist   = (int*)p;      p += align256((size_t)(MAXB + 1) * 4);
    int*      bbase   = (int*)p;      p += align256((size_t)(MAXB + 1) * 4);
    int*      bcursor = (int*)p;      p += align256((size_t)MAXB * 4);
    int*      offsets = (int*)p;      p += align256((size_t)(n + 1) * 4);
    float*    dinv    = (float*)p;    p += align256((size_t)n * 4);
    float*    pooled  = (float*)p;    p += align256((size_t)ngraphs * NCH * 4);
    _Float16* wt1     = (_Float16*)p; p += align256((size_t)NCH * NCH * 2);
    _Float16* wt2     = (_Float16*)p; p += align256((size_t)NCH * NCH * 2);
    int*      tmp     = (int*)p;      p += align256((size_t)E * 4);
    int*      srcs    = (int*)p;      p += align256((size_t)E * 4);
    __half*   xwh     = (__half*)p;   p += align256((size_t)n * NCH * 2);
    __half*   h       = (__half*)p;

    int eblocks = (E + CHUNK - 1) / CHUNK;

    // ---- CSR build via 2-level bucket sort (shared by both layers) ----
    hipMemsetAsync(bhist, 0, (size_t)NB * sizeof(int), stream);
    hipMemsetAsync(pooled, 0, (size_t)ngraphs * NCH * sizeof(float), stream);
    convert_wt<<<32, 256, 0, stream>>>(W1, W2, wt1, wt2);
    bucket_hist<<<eblocks, 256, 0, stream>>>(dst, E, NB, bhist);
    bucket_scan<<<1, MAXB, 0, stream>>>(bhist, NB, bbase, bcursor);
    bucket_scatter<<<eblocks, 256, 0, stream>>>(src, dst, E, NB, bcursor, tmp);
    bucket_finalize<<<NB, 256, 0, stream>>>(tmp, bbase, n, E, NB, offsets, dinv, srcs);

    int gemm_blocks = (n + 63) / 64;

    // ---- layer 1 ----
    gemm64_mfma<float><<<gemm_blocks, 256, 0, stream>>>(x, wt1, dinv, xwh, n);
    gather_fused<<<(n * NCH + 255) / 256, 256, 0, stream>>>(xwh, srcs, offsets, dinv, b1, h, n);

    // ---- layer 2 ----
    gemm64_mfma<__half><<<gemm_blocks, 256, 0, stream>>>(h, wt2, dinv, xwh, n);
    gather_fused<<<(n * NCH + 255) / 256, 256, 0, stream>>>(xwh, srcs, offsets, dinv, b2, h, n);

    // ---- pool + fc ----
    pool_partial<<<POOL_BLOCKS, 256, 0, stream>>>(h, batch, n, pooled);
    fc_out<<<ngraphs, 64, 0, stream>>>(pooled, batch, n, Wfc, bfc, out);
}

// Round 14
// 243.356 us; speedup vs baseline: 1.1422x; 1.1422x over previous
//
#include <hip/hip_runtime.h>
#include <hip/hip_fp16.h>
#include <type_traits>

#define NCH 64
#define MAXB 512   // max buckets (supports n <= 131072)
#define CHUNK 4096 // edges per block in hist/scatter
#define POOL_BLOCKS 2048
#define PADMAX 3840  // 15 pads * 256 nodes per bucket

typedef _Float16 half8 __attribute__((ext_vector_type(8)));
typedef float floatx4 __attribute__((ext_vector_type(4)));

// ---------------- prep: convert W1/W2 to fp16 transposed + zero bhist/pooled/zrow ------
__global__ __launch_bounds__(256) void prep(const float* __restrict__ W1,
                                            const float* __restrict__ W2,
                                            _Float16* __restrict__ wt1,
                                            _Float16* __restrict__ wt2,
                                            int* __restrict__ bhist, int NB,
                                            float* __restrict__ pooled, int npool,
                                            __half* __restrict__ xwhz) {
    int i = blockIdx.x * 256 + threadIdx.x;
    if (i < 4096) {
        int k = i >> 6, c = i & 63;
        wt1[c * NCH + k] = (_Float16)W1[i];
    } else if (i < 8192) {
        int j = i - 4096;
        int k = j >> 6, c = j & 63;
        wt2[c * NCH + k] = (_Float16)W2[j];
    }
    if (i <= NB) bhist[i] = 0;
    if (i < npool) pooled[i] = 0.f;
    if (i < 64) xwhz[i] = __float2half(0.f);
}

// ---------------- A: bucket histogram (bucket = dst >> 8) ----------------
__global__ __launch_bounds__(256) void bucket_hist(const int* __restrict__ dst, int E,
                                                   int NB, int* __restrict__ bhist) {
    __shared__ int lh[MAXB];
    int t = threadIdx.x;
    for (int i = t; i < NB; i += 256) lh[i] = 0;
    __syncthreads();
    int base = blockIdx.x * CHUNK;
    int end = min(base + CHUNK, E);
    for (int i = base + t; i < end; i += 256)
        atomicAdd(&lh[dst[i] >> 8], 1);
    __syncthreads();
    for (int i = t; i < NB; i += 256) {
        int v = lh[i];
        if (v) atomicAdd(&bhist[i], v);
    }
}

// ---------------- B: exclusive scan of bucket counts (1 block) ----------------
__global__ __launch_bounds__(MAXB) void bucket_scan(const int* __restrict__ bhist, int NB,
                                                    int* __restrict__ bbase,
                                                    int* __restrict__ bcursor) {
    __shared__ int s[MAXB];
    int t = threadIdx.x;
    int v = (t < NB) ? bhist[t] : 0;
    s[t] = v;
    __syncthreads();
    for (int o = 1; o < MAXB; o <<= 1) {
        int x = (t >= o) ? s[t - o] : 0;
        __syncthreads();
        s[t] += x;
        __syncthreads();
    }
    int excl = s[t] - v;
    if (t < NB) { bbase[t] = excl; bcursor[t] = excl; }
    if (t == NB - 1) bbase[NB] = s[t];  // = E
}

// ---------------- C: scatter packed (src<<8 | dst&255) into bucket-grouped tmp ----------
__global__ __launch_bounds__(256) void bucket_scatter(const int* __restrict__ src,
                                                      const int* __restrict__ dst, int E,
                                                      int NB, int* __restrict__ bcursor,
                                                      int* __restrict__ tmp) {
    __shared__ int lh[MAXB];
    __shared__ int lbase[MAXB];
    int t = threadIdx.x;
    for (int i = t; i < NB; i += 256) lh[i] = 0;
    __syncthreads();
    int base = blockIdx.x * CHUNK;
    int end = min(base + CHUNK, E);
    for (int i = base + t; i < end; i += 256)
        atomicAdd(&lh[dst[i] >> 8], 1);
    __syncthreads();
    for (int i = t; i < NB; i += 256) {
        int v = lh[i];
        lbase[i] = v ? atomicAdd(&bcursor[i], v) : 0;
        lh[i] = 0;  // reuse as local cursor
    }
    __syncthreads();
    for (int i = base + t; i < end; i += 256) {
        int s_ = src[i], d_ = dst[i];
        int b = d_ >> 8;
        int p = lbase[b] + atomicAdd(&lh[b], 1);
        tmp[p] = (s_ << 8) | (d_ & 255);
    }
}

// ---------------- D: per-bucket finalize: padded CSR + dinv + srcs (byte offsets) -------
// Each node's list padded to a multiple of 16 with zoff (zero-row). offsets[node] packs
// (padded_start << 8) | (padded_len/16). Padded bucket base = bbase[b] + b*PADMAX.
__global__ __launch_bounds__(256) void bucket_finalize(const int* __restrict__ tmp,
                                                       const int* __restrict__ bbase,
                                                       int n, int NB, int zoff,
                                                       int* __restrict__ offsets,
                                                       float* __restrict__ dinv,
                                                       int* __restrict__ srcs) {
    int b = blockIdx.x;
    int t = threadIdx.x;
    __shared__ int ldeg[256];
    __shared__ int lsc[256];
    __shared__ int lcur[256];
    ldeg[t] = 0;
    __syncthreads();
    int s0 = bbase[b], e0 = bbase[b + 1];
    for (int e = s0 + t; e < e0; e += 256)
        atomicAdd(&ldeg[tmp[e] & 255], 1);
    __syncthreads();
    int d = ldeg[t];
    int pd = (d + 15) & ~15;
    lsc[t] = pd;
    __syncthreads();
    for (int o = 1; o < 256; o <<= 1) {
        int x = (t >= o) ? lsc[t - o] : 0;
        __syncthreads();
        lsc[t] += x;
        __syncthreads();
    }
    int pexcl = lsc[t] - pd;
    lcur[t] = pexcl;
    int s0p = s0 + b * PADMAX;
    int node = (b << 8) + t;
    if (node < n) {
        offsets[node] = ((s0p + pexcl) << 8) | (pd >> 4);
        dinv[node] = rsqrtf((float)d + 1.0f);  // +1 self-loop
    }
    __syncthreads();
    for (int e = s0 + t; e < e0; e += 256) {
        int r = tmp[e];
        int p = s0p + atomicAdd(&lcur[r & 255], 1);
        srcs[p] = ((int)(((unsigned)r) >> 8)) << 7;  // byte offset of fp16 row
    }
    __syncthreads();
    for (int q = pexcl + d; q < pexcl + pd; ++q) srcs[s0p + q] = zoff;  // pads
}

// ---------------- MFMA GEMM: Yh[row,:] = half((X[row,:] @ W) * dscale[row]) ------------
template <typename T>
__global__ __launch_bounds__(256) void gemm64_mfma(const T* __restrict__ X,
                                                   const _Float16* __restrict__ wt,
                                                   const float* __restrict__ dscale,
                                                   __half* __restrict__ Y, int n) {
    int tid = threadIdx.x;
    int lane = tid & 63, wv = tid >> 6;
    int row0 = blockIdx.x * 64 + wv * 16;
    if (row0 >= n) return;

    int lrow = lane & 15;
    int kgrp = (lane >> 4) * 8;

    half8 bf[4][2];
#pragma unroll
    for (int ct = 0; ct < 4; ++ct) {
#pragma unroll
        for (int ks = 0; ks < 2; ++ks) {
            bf[ct][ks] = *(const half8*)(wt + (ct * 16 + lrow) * NCH + ks * 32 + kgrp);
        }
    }

    int arow = row0 + lrow;
    half8 af[2];
    if constexpr (std::is_same_v<T, float>) {
        if (arow < n) {
#pragma unroll
            for (int ks = 0; ks < 2; ++ks) {
                const float4* xr = (const float4*)(X + ((size_t)arow << 6) + ks * 32 + kgrp);
                float4 u0 = xr[0], u1 = xr[1];
                half8 a;
                a[0] = (_Float16)u0.x; a[1] = (_Float16)u0.y;
                a[2] = (_Float16)u0.z; a[3] = (_Float16)u0.w;
                a[4] = (_Float16)u1.x; a[5] = (_Float16)u1.y;
                a[6] = (_Float16)u1.z; a[7] = (_Float16)u1.w;
                af[ks] = a;
            }
        } else {
            af[0] = half8{}; af[1] = half8{};
        }
    } else {
        if (arow < n) {
#pragma unroll
            for (int ks = 0; ks < 2; ++ks)
                af[ks] = *(const half8*)((const _Float16*)X + ((size_t)arow << 6) + ks * 32 + kgrp);
        } else {
            af[0] = half8{}; af[1] = half8{};
        }
    }

    floatx4 acc[4] = {floatx4{0,0,0,0}, floatx4{0,0,0,0}, floatx4{0,0,0,0}, floatx4{0,0,0,0}};
#pragma unroll
    for (int ks = 0; ks < 2; ++ks) {
#pragma unroll
        for (int ct = 0; ct < 4; ++ct) {
            acc[ct] = __builtin_amdgcn_mfma_f32_16x16x32_f16(af[ks], bf[ct][ks], acc[ct], 0, 0, 0);
        }
    }

    int rbase = row0 + (lane >> 4) * 4;
    float ds[4];
#pragma unroll
    for (int i = 0; i < 4; ++i) ds[i] = (rbase + i < n) ? dscale[rbase + i] : 0.f;
#pragma unroll
    for (int i = 0; i < 4; ++i) {
        int row = rbase + i;
        if (row < n) {
#pragma unroll
            for (int ct = 0; ct < 4; ++ct) {
                Y[((size_t)row << 6) + ct * 16 + lrow] = __float2half(acc[ct][i] * ds[i]);
            }
        }
    }
}

// ---------------- CSR gather (padded 16-bursts) + self + bias + relu -> fp16 H ----------
__global__ __launch_bounds__(256) void gather_fused(const __half* __restrict__ XWs,
                                                    const int* __restrict__ srcs,
                                                    const int* __restrict__ offsets,
                                                    const float* __restrict__ dinv,
                                                    const float* __restrict__ b,
                                                    __half* __restrict__ H, int n) {
    int wid  = (blockIdx.x * 256 + threadIdx.x) >> 6;  // node
    int lane = threadIdx.x & 63;                       // channel
    if (wid >= n) return;
    const char* tab = (const char*)(XWs + lane);       // lane-offset base
    int pk = offsets[wid];
    int base = pk >> 8;
    int nit = pk & 255;
    float dv = dinv[wid];
    float bias = b[lane];
    float self = __half2float(*(const __half*)(tab + (wid << 7)));
    float a0 = 0.f, a1 = 0.f, a2 = 0.f, a3 = 0.f;
    for (int it = 0; it < nit; ++it) {
        int e = base + (it << 4);
        float t0  = __half2float(*(const __half*)(tab + srcs[e + 0]));
        float t1  = __half2float(*(const __half*)(tab + srcs[e + 1]));
        float t2  = __half2float(*(const __half*)(tab + srcs[e + 2]));
        float t3  = __half2float(*(const __half*)(tab + srcs[e + 3]));
        float t4  = __half2float(*(const __half*)(tab + srcs[e + 4]));
        float t5  = __half2float(*(const __half*)(tab + srcs[e + 5]));
        float t6  = __half2float(*(const __half*)(tab + srcs[e + 6]));
        float t7  = __half2float(*(const __half*)(tab + srcs[e + 7]));
        float t8  = __half2float(*(const __half*)(tab + srcs[e + 8]));
        float t9  = __half2float(*(const __half*)(tab + srcs[e + 9]));
        float t10 = __half2float(*(const __half*)(tab + srcs[e + 10]));
        float t11 = __half2float(*(const __half*)(tab + srcs[e + 11]));
        float t12 = __half2float(*(const __half*)(tab + srcs[e + 12]));
        float t13 = __half2float(*(const __half*)(tab + srcs[e + 13]));
        float t14 = __half2float(*(const __half*)(tab + srcs[e + 14]));
        float t15 = __half2float(*(const __half*)(tab + srcs[e + 15]));
        a0 += t0 + t4 + t8  + t12;
        a1 += t1 + t5 + t9  + t13;
        a2 += t2 + t6 + t10 + t14;
        a3 += t3 + t7 + t11 + t15;
    }
    float v = (self + ((a0 + a1) + (a2 + a3))) * dv + bias;
    H[((size_t)wid << 6) + lane] = __float2half(v > 0.0f ? v : 0.0f);
}

// ---------------- pool stage 1: per-wave contiguous slice -> atomic flush per run -------
__global__ __launch_bounds__(256) void pool_partial(const __half* __restrict__ H,
                                                    const int* __restrict__ batch, int n,
                                                    float* __restrict__ pooled) {
    int gwave = blockIdx.x * 4 + (threadIdx.x >> 6);
    int lane  = threadIdx.x & 63;
    int nwaves = POOL_BLOCKS * 4;
    int per = (n + nwaves - 1) / nwaves;
    int start = gwave * per;
    int end = min(start + per, n);
    if (start >= end) return;
    int cur = batch[start];
    float acc = 0.f;
    for (int i = start; i < end; ++i) {
        int g = batch[i];
        if (g != cur) {
            atomicAdd(&pooled[(cur << 6) + lane], acc);
            acc = 0.f;
            cur = g;
        }
        acc += __half2float(H[((size_t)i << 6) + lane]);
    }
    atomicAdd(&pooled[(cur << 6) + lane], acc);
}

// ---------------- pool stage 2: mean + FC + relu (one wave per graph) ----------------
__global__ __launch_bounds__(64) void fc_out(const float* __restrict__ pooled,
                                             const int* __restrict__ batch, int n,
                                             const float* __restrict__ Wfc,
                                             const float* __restrict__ bfc,
                                             float* __restrict__ out) {
    int g = blockIdx.x;
    int c = threadIdx.x;
    int lo = 0, hi = n;
    while (lo < hi) { int m = (lo + hi) >> 1; if (batch[m] < g) lo = m + 1; else hi = m; }
    int start = lo;
    hi = n;
    while (lo < hi) { int m = (lo + hi) >> 1; if (batch[m] < g + 1) lo = m + 1; else hi = m; }
    int count = lo - start;

    __shared__ float ps[64];
    float inv = 1.0f / (float)(count > 1 ? count : 1);
    ps[c] = pooled[(g << 6) + c] * inv;
    __syncthreads();
    float acc = bfc[c];
#pragma unroll
    for (int k = 0; k < 64; ++k) acc += ps[k] * Wfc[k * NCH + c];
    out[(g << 6) + c] = acc > 0.0f ? acc : 0.0f;
}

static inline size_t align256(size_t x) { return (x + 255) & ~(size_t)255; }

extern "C" void kernel_launch(void* const* d_in, const int* in_sizes, int n_in,
                              void* d_out, int out_size, void* d_ws, size_t ws_size,
                              hipStream_t stream) {
    const float* x     = (const float*)d_in[0];
    const int*   ei    = (const int*)d_in[1];
    const int*   batch = (const int*)d_in[2];
    const float* W1    = (const float*)d_in[3];
    const float* b1    = (const float*)d_in[4];
    const float* W2    = (const float*)d_in[5];
    const float* b2    = (const float*)d_in[6];
    const float* Wfc   = (const float*)d_in[7];
    const float* bfc   = (const float*)d_in[8];
    float* out = (float*)d_out;

    int E = in_sizes[1] / 2;
    int n = in_sizes[0] / NCH;
    int ngraphs = out_size / NCH;
    const int* src = ei;
    const int* dst = ei + E;
    int NB = (n + 255) >> 8;
    int npool = ngraphs * NCH;

    char* p = (char*)d_ws;
    int*      bhist   = (int*)p;      p += align256((size_t)(MAXB + 1) * 4);
    int*      bbase   = (int*)p;      p += align256((size_t)(MAXB + 1) * 4);
    int*      bcursor = (int*)p;      p += align256((size_t)MAXB * 4);
    int*      offsets = (int*)p;      p += align256((size_t)(n + 1) * 4);
    float*    dinv    = (float*)p;    p += align256((size_t)n * 4);
    float*    pooled  = (float*)p;    p += align256((size_t)npool * 4);
    _Float16* wt1     = (_Float16*)p; p += align256((size_t)NCH * NCH * 2);
    _Float16* wt2     = (_Float16*)p; p += align256((size_t)NCH * NCH * 2);
    int*      tmp     = (int*)p;      p += align256((size_t)E * 4);
    int*      srcs    = (int*)p;      p += align256((size_t)(E + (size_t)NB * PADMAX) * 4);
    __half*   xwh     = (__half*)p;   p += align256(((size_t)n + 1) * NCH * 2);
    __half*   h       = (__half*)p;

    int eblocks = (E + CHUNK - 1) / CHUNK;
    int zoff = n << 7;  // byte offset of the reserved zero row

    // ---- prep + CSR build via 2-level bucket sort (shared by both layers) ----
    prep<<<32, 256, 0, stream>>>(W1, W2, wt1, wt2, bhist, NB, pooled, npool, xwh + (size_t)n * NCH);
    bucket_hist<<<eblocks, 256, 0, stream>>>(dst, E, NB, bhist);
    bucket_scan<<<1, MAXB, 0, stream>>>(bhist, NB, bbase, bcursor);
    bucket_scatter<<<eblocks, 256, 0, stream>>>(src, dst, E, NB, bcursor, tmp);
    bucket_finalize<<<NB, 256, 0, stream>>>(tmp, bbase, n, NB, zoff, offsets, dinv, srcs);

    int gemm_blocks = (n + 63) / 64;

    // ---- layer 1 ----
    gemm64_mfma<float><<<gemm_blocks, 256, 0, stream>>>(x, wt1, dinv, xwh, n);
    gather_fused<<<(n * NCH + 255) / 256, 256, 0, stream>>>(xwh, srcs, offsets, dinv, b1, h, n);

    // ---- layer 2 ----
    gemm64_mfma<__half><<<gemm_blocks, 256, 0, stream>>>(h, wt2, dinv, xwh, n);
    gather_fused<<<(n * NCH + 255) / 256, 256, 0, stream>>>(xwh, srcs, offsets, dinv, b2, h, n);

    // ---- pool + fc ----
    pool_partial<<<POOL_BLOCKS, 256, 0, stream>>>(h, batch, n, pooled);
    fc_out<<<ngraphs, 64, 0, stream>>>(pooled, batch, n, Wfc, bfc, out);
}